// Round 1
// baseline (384.511 us; speedup 1.0000x reference)
//
#include <hip/hip_runtime.h>

// GeneralizedCrossEntropy: loss[k] = mean_b (1 - d[b,k]^Q)/Q
// where d[b,k] = softmax_c(logits[b, :, t[b,k]])[k], t = targets[b, 0..C-1]
// Shapes fixed by the problem: B=16, C=21, H=W=512 -> N=262144.

#define GCE_Q 0.8f

__global__ __launch_bounds__(64) void gce_kernel(
    const float* __restrict__ logits,   // [B, C, N] fp32
    const int*   __restrict__ targets,  // [B, N] int32
    float*       __restrict__ out)      // [C] fp32
{
    constexpr int B = 16;
    constexpr int C = 21;
    constexpr long long N = 512LL * 512LL;

    const int k    = blockIdx.x;   // output channel, 0..C-1
    const int lane = threadIdx.x;  // 0..63; lanes 0..B-1 active

    float val = 0.0f;
    if (lane < B) {
        const int b = lane;
        const int t = targets[(long long)b * N + (long long)k];
        const float* __restrict__ col =
            logits + (long long)b * C * N + (long long)t;

        // Gather the 21-element logit column (stride N), fully unrolled so
        // everything stays in registers; capture l[k] with a predicate to
        // avoid dynamic register indexing.
        float m  = -INFINITY;
        float lk = 0.0f;
        float l[C];
#pragma unroll
        for (int c = 0; c < C; ++c) {
            l[c] = col[(long long)c * N];
            m = fmaxf(m, l[c]);
            if (c == k) lk = l[c];
        }
        float s = 0.0f;
#pragma unroll
        for (int c = 0; c < C; ++c) {
            s += __expf(l[c] - m);
        }
        const float d = __expf(lk - m) / s;
        val = (1.0f - __powf(d, GCE_Q)) / GCE_Q;
    }

    // Reduce over the 64-lane wave (only lanes < B contribute nonzero).
#pragma unroll
    for (int off = 32; off > 0; off >>= 1) {
        val += __shfl_down(val, off, 64);
    }
    if (lane == 0) {
        out[k] = val / (float)B;
    }
}

extern "C" void kernel_launch(void* const* d_in, const int* in_sizes, int n_in,
                              void* d_out, int out_size, void* d_ws, size_t ws_size,
                              hipStream_t stream) {
    const float* logits  = (const float*)d_in[0];
    const int*   targets = (const int*)d_in[1];
    float*       out     = (float*)d_out;

    // One block per output channel; one wave per block.
    gce_kernel<<<dim3(21), dim3(64), 0, stream>>>(logits, targets, out);
}